// Round 3
// baseline (722.997 us; speedup 1.0000x reference)
//
#include <hip/hip_runtime.h>
#include <hip/hip_bf16.h>

// DeStationaryAttention: y = softmax((xq Wq + bq)(xk Wk + bk)^T / 8) (xv Wv + bv)
// B=4 H=8 L=2048 Dk=64 Dm=512. All I/O float32.
// Outputs: out [4,2048,512] ++ attn [4,8,2048,2048], f32.
// Internal workspace Q/K/V^T (and bf16 copies of W^T, X) for MFMA.

using u16 = unsigned short;
using u32 = unsigned int;

typedef __attribute__((ext_vector_type(4))) float  f32x4;
typedef __attribute__((ext_vector_type(8))) short  s16x8;
typedef __attribute__((ext_vector_type(4))) short  s16x4;
typedef __attribute__((ext_vector_type(2))) unsigned int u32x2;
typedef __attribute__((ext_vector_type(4))) unsigned int u32x4;

#define MFMA16(a,b,c) __builtin_amdgcn_mfma_f32_16x16x32_bf16(a,b,c,0,0,0)

#if __has_builtin(__builtin_amdgcn_mfma_f32_16x16x16bf16_1k)
#define MFMA1616(a,b,c) __builtin_amdgcn_mfma_f32_16x16x16bf16_1k(a,b,c,0,0,0)
#else
__device__ __forceinline__ f32x4 MFMA1616(s16x4 a, s16x4 b, f32x4 c){
  asm("v_mfma_f32_16x16x16_bf16 %0, %1, %2, %0" : "+v"(c) : "v"(a), "v"(b));
  return c;
}
#endif

__device__ __forceinline__ u16 f2bf(float f){
  u32 x; __builtin_memcpy(&x, &f, 4);
  x += 0x7FFFu + ((x >> 16) & 1u);   // RNE
  return (u16)(x >> 16);
}
__device__ __forceinline__ u32 pk2(float a, float b){
  return (u32)f2bf(a) | ((u32)f2bf(b) << 16);
}
#if __has_builtin(__builtin_amdgcn_exp2f)
__device__ __forceinline__ float ex2(float x){ return __builtin_amdgcn_exp2f(x); }
#else
__device__ __forceinline__ float ex2(float x){ return exp2f(x); }
#endif

// async global->LDS, 16B per lane; dest is wave-uniform base (+ lane*16 in HW)
__device__ __forceinline__ void async16(const u16* src, char* wavebase, int lane){
#if __has_builtin(__builtin_amdgcn_global_load_lds)
  __builtin_amdgcn_global_load_lds(
      (const __attribute__((address_space(1))) unsigned int*)src,
      (__attribute__((address_space(3))) unsigned int*)wavebase, 16, 0, 0);
#else
  *(u32x4*)(wavebase + lane*16) = *(const u32x4*)src;
#endif
}

// softmax scale: 1/sqrt(64) folded with log2(e) for native v_exp_f32 (2^x)
#define SCALE2 0.18033688f

// ---------------------------------------------------------------------------
// Kernel 0 (prep): fused
//  blocks [0,768):   transpose+convert W: Wt[n][k] = bf16(W[k][n])  (3x 512x512)
//  blocks [768,6912): convert X (q/k/v inputs) f32 -> bf16, 8 elems/thread
// ---------------------------------------------------------------------------
__global__ __launch_bounds__(256) void prep_kernel(
    const float* __restrict__ Wq, const float* __restrict__ Wk, const float* __restrict__ Wv,
    const float* __restrict__ q_in, const float* __restrict__ k_in, const float* __restrict__ v_in,
    u16* __restrict__ Wt, u16* __restrict__ Xb)
{
  const int b = blockIdx.x, t = threadIdx.x;
  if (b < 768){
    int zi = b >> 8, rem = b & 255;
    const float* W = zi==0 ? Wq : (zi==1 ? Wk : Wv);
    u16*         T = Wt + zi*262144;
    __shared__ u16 tls[32][33];
    int x = t & 31, y0 = t >> 5;
    int bx = (rem & 15)*32, by = (rem >> 4)*32;
    #pragma unroll
    for (int i=0;i<4;i++){ int y=y0+i*8; tls[y][x] = f2bf(W[(by+y)*512 + bx + x]); }
    __syncthreads();
    #pragma unroll
    for (int i=0;i<4;i++){ int y=y0+i*8; T[(bx+y)*512 + by + x] = tls[x][y]; }
  } else {
    int g = (b - 768)*256 + t;              // 8-elem chunk index
    int mode = g >> 19, off = g & 524287;   // 524288 chunks per input
    const float* src = mode==0 ? q_in : (mode==1 ? k_in : v_in);
    const float* sp = src + (size_t)off*8;
    f32x4 a = *(const f32x4*)sp;
    f32x4 c = *(const f32x4*)(sp+4);
    u32x4 o = { pk2(a[0],a[1]), pk2(a[2],a[3]), pk2(c[0],c[1]), pk2(c[2],c[3]) };
    *(u32x4*)(Xb + (size_t)mode*4194304 + (size_t)off*8) = o;
  }
}

// ---------------------------------------------------------------------------
// Kernel 1: fused QKV projection GEMMs (K=512), 128x128 tiles, 4 waves/block.
// Both operands now bf16 in global; staged via global_load_lds width=16 with
// source-pre-swizzled addresses (LDS dest linear; read swizzle unchanged).
// mode 0/1 (Q/K): C[n][l] = Wt x^T ; mode 2 (V): C[l][n] = x Wt^T.
// ---------------------------------------------------------------------------
__global__ __launch_bounds__(256,4) void proj_kernel(
    const u16* __restrict__ Xb, const u16* __restrict__ Wt,
    const float* __restrict__ bq, const float* __restrict__ bk, const float* __restrict__ bv,
    u16* __restrict__ Qo, u16* __restrict__ Ko, u16* __restrict__ Vto)
{
  const int mode = blockIdx.z;
  const int lt = blockIdx.x;       // 0..63  (128 rows of the 8192 token rows)
  const int nt = blockIdx.y;       // 0..3   (128 of the 512 output cols)
  const u16* Xm = Xb + (size_t)mode*4194304;
  const u16* Wm = Wt + (size_t)mode*262144;
  const float* bias = mode==0 ? bq : (mode==1 ? bk : bv);

  __shared__ __align__(16) u16 As[128*32];
  __shared__ __align__(16) u16 Bs[128*32];

  const u16* Ab = (mode<2) ? Wm : Xm;  const int Ar0 = (mode<2) ? nt*128 : lt*128;
  const u16* Bb = (mode<2) ? Xm : Wm;  const int Br0 = (mode<2) ? lt*128 : nt*128;

  const int t = threadIdx.x;
  const int w = t>>6, lane = t&63, l16 = lane&15, quad = lane>>4;
  const int am = (w&1)*64, bn = (w>>1)*64;

  f32x4 acc[4][4];
  #pragma unroll
  for (int i=0;i<4;i++)
    #pragma unroll
    for (int j=0;j<4;j++) acc[i][j] = (f32x4){0.f,0.f,0.f,0.f};

  for (int kk=0; kk<512; kk+=32){
    __syncthreads();
    // stage A,B tiles: 512 16B chunks each; wave w, instr h -> dest chunks
    // (w*2+h)*64 + lane. LDS slot s4 holds source chunk s4 ^ f(row).
    #pragma unroll
    for (int h=0;h<2;h++){
      int cidx = (w*2+h)*64 + lane;
      int row = cidx>>2, s4 = cidx&3;
      int c4 = s4 ^ (row&3) ^ ((row>>2)&3);
      async16(Ab + (size_t)(Ar0+row)*512 + kk + c4*8, (char*)As + (w*2+h)*1024, lane);
    }
    #pragma unroll
    for (int h=0;h<2;h++){
      int cidx = (w*2+h)*64 + lane;
      int row = cidx>>2, s4 = cidx&3;
      int c4 = s4 ^ (row&3) ^ ((row>>2)&3);
      async16(Bb + (size_t)(Br0+row)*512 + kk + c4*8, (char*)Bs + (w*2+h)*1024, lane);
    }
    __syncthreads();
    s16x8 fa[4], fb[4];
    #pragma unroll
    for (int i=0;i<4;i++){
      int ra = am + i*16 + l16;
      fa[i] = *(const s16x8*)((const char*)As + ra*64 + ((quad ^ (ra&3) ^ ((ra>>2)&3))*16));
      int rb = bn + i*16 + l16;
      fb[i] = *(const s16x8*)((const char*)Bs + rb*64 + ((quad ^ (rb&3) ^ ((rb>>2)&3))*16));
    }
    #pragma unroll
    for (int i=0;i<4;i++)
      #pragma unroll
      for (int j=0;j<4;j++)
        acc[i][j] = MFMA16(fa[i], fb[j], acc[i][j]);
  }

  if (mode < 2){
    u16* Out = mode==0 ? Qo : Ko;
    #pragma unroll
    for (int i=0;i<4;i++){
      int n0 = nt*128 + am + i*16 + quad*4;
      float b4[4];
      #pragma unroll
      for (int r=0;r<4;r++) b4[r] = bias[n0+r];
      int h = n0>>6, d0 = n0&63;
      #pragma unroll
      for (int j=0;j<4;j++){
        int lg = lt*128 + bn + j*16 + l16;
        int b = lg>>11, ll = lg&2047;
        u32x2 pk = { pk2(acc[i][j][0]+b4[0], acc[i][j][1]+b4[1]),
                     pk2(acc[i][j][2]+b4[2], acc[i][j][3]+b4[3]) };
        *(u32x2*)(Out + ((size_t)(((b<<3)+h)*2048 + ll)<<6) + d0) = pk;
      }
    }
  } else {
    #pragma unroll
    for (int j=0;j<4;j++){
      int nv = nt*128 + bn + j*16 + l16;
      float bvv = bias[nv];
      int h = nv>>6, d = nv&63;
      #pragma unroll
      for (int i=0;i<4;i++){
        int lg = lt*128 + am + i*16 + quad*4;
        int b = lg>>11, ll = lg&2047;
        u32x2 pk = { pk2(acc[i][j][0]+bvv, acc[i][j][1]+bvv),
                     pk2(acc[i][j][2]+bvv, acc[i][j][3]+bvv) };
        *(u32x2*)(Vto + ((size_t)(((b<<3)+h)*64 + d)<<11) + ll) = pk;
      }
    }
  }
}

// ---------------------------------------------------------------------------
// Kernel 2: attention (512 threads / 8 waves, 1 barrier per k-tile,
// register-resident Q and P-fragments, double-buffered K/V staging).
//  - normalization folded into the exponent: w = 2^(s*SCALE2 - log2(l))
//  - softmax + PV merged per c-group (lower register pressure)
//  - s_setprio(1) around QK MFMA clusters (T5)
// ---------------------------------------------------------------------------
__global__ __launch_bounds__(512,4) void attn_kernel(
    const u16* __restrict__ Q, const u16* __restrict__ K, const u16* __restrict__ Vt,
    float* __restrict__ out, float* __restrict__ attn)
{
  const int qt = blockIdx.x;                   // 0..15
  const int bh = blockIdx.z*8 + blockIdx.y;    // b*8+h
  const int q0 = qt*128;
  const u16* Qg = Q  + (size_t)bh*2048*64;
  const u16* Kg = K  + (size_t)bh*2048*64;
  const u16* Vg = Vt + (size_t)bh*64*2048;
  float* attng = attn + ((size_t)bh*2048 + q0)*2048;

  __shared__ __align__(128) char smem[65536];
  float* Ls = (float*)(smem + 49152);          // aliases Vs buf1; dead before use
  float* Os = (float*)smem;                    // [128][68] f32, end only

  const int t = threadIdx.x;
  const int w = t>>6, lane = t&63, l16 = lane&15, quad = lane>>4;
  const int coff = (w&1)*64, roff = (w>>1)*32;

  if (t < 128) Ls[t] = 0.f;
  __syncthreads();

  // Q fragments resident in registers: rows roff..roff+31, full K=64
  s16x8 qf[2][2];
  #pragma unroll
  for (int kc=0;kc<2;kc++)
    #pragma unroll
    for (int ri=0;ri<2;ri++)
      qf[kc][ri] = *(const s16x8*)(Qg + (size_t)(q0 + roff + ri*16 + l16)*64 + (kc*4+quad)*8);

  // prefetch tile 0 of K,V into buffer 0 (in flight across pass 1)
  #pragma unroll
  for (int j=0;j<2;j++){
    int id = j*512 + t; int row = id>>3, ch = id&7;
    async16(Kg + (size_t)row*64 + ((ch ^ (row&7))*8), smem + (j*512 + w*64)*16, lane);
  }
  #pragma unroll
  for (int j=0;j<2;j++){
    int id = j*512 + t; int row = id>>4, ch = id&15;
    async16(Vg + (size_t)row*2048 + ((ch ^ (row&15))*8), smem + 32768 + (j*512 + w*64)*16, lane);
  }

  // ------------------------------ pass 1: row sums (no barriers) -----------
  float lsum[2] = {0.f, 0.f};
  for (int kt=0; kt<16; kt++){
    f32x4 s[4][2];
    #pragma unroll
    for (int ci=0;ci<4;ci++)
      #pragma unroll
      for (int ri=0;ri<2;ri++) s[ci][ri] = (f32x4){0.f,0.f,0.f,0.f};
    #pragma unroll
    for (int kc=0;kc<2;kc++){
      s16x8 fa[4];
      #pragma unroll
      for (int ci=0;ci<4;ci++){
        int rc = kt*128 + coff + ci*16 + l16;
        fa[ci] = *(const s16x8*)(Kg + (size_t)rc*64 + (kc*4+quad)*8);
      }
      __builtin_amdgcn_s_setprio(1);
      #pragma unroll
      for (int ci=0;ci<4;ci++)
        #pragma unroll
        for (int ri=0;ri<2;ri++)
          s[ci][ri] = MFMA16(fa[ci], qf[kc][ri], s[ci][ri]);
      __builtin_amdgcn_s_setprio(0);
    }
    #pragma unroll
    for (int ri=0;ri<2;ri++){
      float ps = 0.f;
      #pragma unroll
      for (int ci=0;ci<4;ci++)
        #pragma unroll
        for (int r=0;r<4;r++) ps += ex2(s[ci][ri][r]*SCALE2);
      lsum[ri] += ps;
    }
  }
  #pragma unroll
  for (int ri=0;ri<2;ri++){
    float v = lsum[ri];
    v += __shfl_xor(v, 16, 64);
    v += __shfl_xor(v, 32, 64);
    if (quad == 0) atomicAdd(&Ls[roff + ri*16 + l16], v);
  }
  __syncthreads();                 // Ls complete; prologue prefetch drained
  float nm2[2];                    // -log2(denominator), folded into exponent
  #pragma unroll
  for (int ri=0;ri<2;ri++) nm2[ri] = -__log2f(Ls[roff + ri*16 + l16]);
  __syncthreads();                 // all Ls reads done before Vs buf1 prefetch

  // ------------------------------ pass 2 -----------------------------------
  f32x4 o[2][4];
  #pragma unroll
  for (int ri=0;ri<2;ri++)
    #pragma unroll
    for (int ni=0;ni<4;ni++) o[ri][ni] = (f32x4){0.f,0.f,0.f,0.f};

  int cur = 0;
  for (int kt=0; kt<16; kt++){
    char* Kc = smem + cur*16384;
    char* Vc = smem + 32768 + cur*16384;
    char* Kn = smem + (cur^1)*16384;
    char* Vn = smem + 32768 + (cur^1)*16384;
    if (kt < 15){                  // issue prefetch for kt+1 (async)
      #pragma unroll
      for (int j=0;j<2;j++){
        int id = j*512 + t; int row = id>>3, ch = id&7;
        async16(Kg + (size_t)((kt+1)*128+row)*64 + ((ch ^ (row&7))*8),
                Kn + (j*512 + w*64)*16, lane);
      }
      #pragma unroll
      for (int j=0;j<2;j++){
        int id = j*512 + t; int row = id>>4, ch = id&15;
        async16(Vg + (size_t)row*2048 + (kt+1)*128 + ((ch ^ (row&15))*8),
                Vn + (j*512 + w*64)*16, lane);
      }
    }
    // S^T = K Q^T from LDS K + register Q
    f32x4 s[4][2];
    #pragma unroll
    for (int ci=0;ci<4;ci++)
      #pragma unroll
      for (int ri=0;ri<2;ri++) s[ci][ri] = (f32x4){0.f,0.f,0.f,0.f};
    #pragma unroll
    for (int kc=0;kc<2;kc++){
      s16x8 fa[4];
      #pragma unroll
      for (int ci=0;ci<4;ci++){
        int rc = coff + ci*16 + l16;
        fa[ci] = *(const s16x8*)(Kc + rc*128 + (((kc*4+quad) ^ (rc&7))*16));
      }
      __builtin_amdgcn_s_setprio(1);
      #pragma unroll
      for (int ci=0;ci<4;ci++)
        #pragma unroll
        for (int ri=0;ri<2;ri++)
          s[ci][ri] = MFMA16(fa[ci], qf[kc][ri], s[ci][ri]);
      __builtin_amdgcn_s_setprio(0);
    }
    // merged softmax + PV per c-group: w = 2^(s*SCALE2 + nm2) -> store f32,
    // pack bf16 A-frag, feed PV MFMA directly from registers.
    #pragma unroll
    for (int cc=0;cc<4;cc++){
      s16x4 pa[2];
      #pragma unroll
      for (int ri=0;ri<2;ri++){
        f32x4 e;
        #pragma unroll
        for (int r=0;r<4;r++) e[r] = ex2(__builtin_fmaf(s[cc][ri][r], SCALE2, nm2[ri]));
        int rr = roff + ri*16 + l16;
        int c0 = coff + cc*16 + quad*4;
        *(f32x4*)(attng + (size_t)rr*2048 + kt*128 + c0) = e;
        s16x4 p;
        #pragma unroll
        for (int r=0;r<4;r++) p[r] = (short)f2bf(e[r]);
        pa[ri] = p;
      }
      #pragma unroll
      for (int ni=0;ni<4;ni++){
        int dd = ni*16 + l16;
        int ch = ((coff>>3) + cc*2 + (quad>>1)) ^ (dd&15);
        s16x4 vb = *(const s16x4*)(Vc + dd*256 + ch*16 + (quad&1)*8);
        #pragma unroll
        for (int ri=0;ri<2;ri++) o[ri][ni] = MFMA1616(pa[ri], vb, o[ri][ni]);
      }
    }
    __syncthreads();               // drain prefetch; order buffer reuse
    cur ^= 1;
  }

  // cross-wave reduction of c-half partials (pairs w, w^1 share roff)
  if (w & 1){
    #pragma unroll
    for (int ri=0;ri<2;ri++)
      #pragma unroll
      for (int ni=0;ni<4;ni++)
        #pragma unroll
        for (int r=0;r<4;r++)
          Os[(roff + ri*16 + quad*4 + r)*68 + ni*16 + l16] = o[ri][ni][r];
  }
  __syncthreads();
  if (!(w & 1)){
    float* og = out + ((size_t)(bh>>3)*2048 + q0)*512 + (bh&7)*64;
    #pragma unroll
    for (int ri=0;ri<2;ri++)
      #pragma unroll
      for (int ni=0;ni<4;ni++)
        #pragma unroll
        for (int r=0;r<4;r++){
          int rr = roff + ri*16 + quad*4 + r;
          int dd = ni*16 + l16;
          og[(size_t)rr*512 + dd] = o[ri][ni][r] + Os[rr*68 + dd];
        }
  }
}

// ---------------------------------------------------------------------------
extern "C" void kernel_launch(void* const* d_in, const int* in_sizes, int n_in,
                              void* d_out, int out_size, void* d_ws, size_t ws_size,
                              hipStream_t stream) {
  (void)in_sizes; (void)n_in; (void)out_size; (void)ws_size;
  const float* q_in = (const float*)d_in[0];
  const float* k_in = (const float*)d_in[1];
  const float* v_in = (const float*)d_in[2];
  const float* Wq   = (const float*)d_in[3];
  const float* bq   = (const float*)d_in[4];
  const float* Wk   = (const float*)d_in[5];
  const float* bk   = (const float*)d_in[6];
  const float* Wv   = (const float*)d_in[7];
  const float* bv   = (const float*)d_in[8];

  u16* ws  = (u16*)d_ws;
  u16* Wt  = ws;                          // 3 * 512*512 bf16          (1.5 MB)
  u16* Qw  = ws + 786432;                 // [4,8,2048,64] bf16        (8 MB)
  u16* Kw  = Qw + 4194304;                // [4,8,2048,64] bf16        (8 MB)
  u16* Vtw = Kw + 4194304;                // [4,8,64,2048] bf16        (8 MB)
  u16* Xb  = Vtw + 4194304;               // 3 x [8192,512] bf16       (25 MB)

  float* outp  = (float*)d_out;           // [4,2048,512]
  float* attnp = outp + 4194304;          // [4,8,2048,2048]

  prep_kernel<<<6912, 256, 0, stream>>>(Wq, Wk, Wv, q_in, k_in, v_in, Wt, Xb);
  proj_kernel<<<dim3(64,4,3), 256, 0, stream>>>(Xb, Wt, bq, bk, bv, Qw, Kw, Vtw);
  attn_kernel<<<dim3(16,8,4), 512, 0, stream>>>(Qw, Kw, Vtw, outp, attnp);
}